// Round 14
// baseline (507.861 us; speedup 1.0000x reference)
//
#include <hip/hip_runtime.h>

#define T_ 30
#define H_ 41
#define WD_ 2048
#define NSEC 9
#define FM 50
#define WP 502
#define THRESH 23.0f
#define POOLED_SIZE (NSEC * T_ * FM * WP)   // 6,777,000
#define MARGIN 0.0625f                      // ~19 sigma of fp16-input error
#define NFRAG 17280                         // 9 sec * 64 fm * 30 tap-octets
#define XC 296                              // LDS cols per shift plane
#define XROWS 9

typedef _Float16 half8 __attribute__((ext_vector_type(8)));
typedef _Float16 half4v __attribute__((ext_vector_type(4)));
typedef float f32x16 __attribute__((ext_vector_type(16)));

__device__ __forceinline__ unsigned short f32_to_f16u(float f) {
    union { _Float16 h; unsigned short u; } cv;
    cv.h = (_Float16)f;
    return cv.u;
}

// ---------------- prep: W -> 32x32x16 fp16 MFMA frags (single array) ------
// gid = (sec*64 + fm)*30 + oct; octet taps t0=8*oct..+7. Also inits keys.
__global__ __launch_bounds__(256) void prep_kernel(
    const float* __restrict__ Wg, int* __restrict__ wsi,
    uint4* __restrict__ wf)
{
    const int gid = blockIdx.x * 256 + threadIdx.x;
    if (gid < NSEC) wsi[gid] = 0x7fffffff;
    if (gid >= NFRAG) return;
    const int oct = gid % 30;
    const int fm  = (gid / 30) & 63;
    const int sec = gid / 1920;
    const int t0  = oct * 8;
    const bool valid = fm < FM;
    const float* wp = Wg + ((size_t)sec * FM + (valid ? fm : 0)) * 240 + t0;
    float4 wa = *reinterpret_cast<const float4*>(wp);
    float4 wb = *reinterpret_cast<const float4*>(wp + 4);
    float f[8] = {wa.x, wa.y, wa.z, wa.w, wb.x, wb.y, wb.z, wb.w};
    unsigned short hu[8];
#pragma unroll
    for (int i = 0; i < 8; ++i)
        hu[i] = f32_to_f16u(valid ? f[i] : 0.f);
    wf[gid] = *reinterpret_cast<uint4*>(hu);
}

// ---------------- Kernel A: fp16 MFMA conv + fire + pool + argmin ---------
// R12/R13 verified tiling (8 waves = j_p x ft; res pairs (rr, rr+4); A layout
// m=lane&31, k=8*(lane>>5)+j; C/D col=lane&31, row=(reg&3)+8*(reg>>2)+
// 4*(lane>>5)). R14: fp16 single-precision inputs — x error <= 2^-12,
// w error <= 2^-11|w| -> pot sigma ~0.003; MARGIN 0.0625 (~19 sigma) and the
// fp32 repair path catch all flips. Deletes: xl array (LDS 45->23 KB, occ
// 2->3 blocks/CU), 2 of 3 MFMAs, half the LDS reads, half the staging VALU.
__global__ __launch_bounds__(512) void conv_pool_kernel(
    const float* __restrict__ x, const float* __restrict__ Wg,
    const uint4* __restrict__ wf,
    float* __restrict__ out, int* __restrict__ keys)
{
    __shared__ __align__(16) unsigned short xh[4][XROWS][XC];  // 20.8 KB
    __shared__ unsigned lmask[8][64];
    __shared__ int wmin[8];

    const int b       = blockIdx.x;
    const int coltile = b & 7;             // 8 coltiles * 256 pot cols
    const int tt      = (b >> 3) % T_;
    const int sec     = b / 240;
    const int w0      = coltile * 256;
    const int rowbase = 4 * sec;           // rows used <= 40 < 41
    const int tid     = threadIdx.x;

    // ---- stage x: 9 rows x 296 cols -> fp16, 4 shifted copies ----
    for (int i = tid; i < XROWS * 74; i += 512) {
        const int row = i / 74;
        const int c4  = i % 74;
        const int gc  = w0 + 4 * c4;
        float4 v;
        if (gc + 3 < WD_) {
            v = *reinterpret_cast<const float4*>(
                x + ((size_t)tt * H_ + rowbase + row) * WD_ + gc);
        } else {
            v.x = v.y = v.z = v.w = 0.f;
        }
        float f[4] = {v.x, v.y, v.z, v.w};
        unsigned short hq[4];
#pragma unroll
        for (int e = 0; e < 4; ++e) hq[e] = f32_to_f16u(f[e]);
#pragma unroll
        for (int S = 0; S < 4; ++S)
#pragma unroll
            for (int e = 0; e < 4; ++e) {
                const int j = 4 * c4 + e - S;
                if (j >= 0 && j < XC) xh[S][row][j] = hq[e];
            }
    }
    __syncthreads();

    const int L   = tid & 63;
    const int wid = tid >> 6;
    const int j_p = wid & 3;        // pot row
    const int ft  = wid >> 2;       // fm tile (32 fm each)
    const int n32 = L & 31;         // A: m; B/C/D: n
    const int hA  = L >> 5;         // k-offset 8*hA; C/D row += 4*hA

    const int fbase = (sec * 64 + ft * 32 + n32) * 30 + hA;
    const int aoff_base = j_p * XC + 8 * hA + 8 * n32;

    unsigned mask = 0;

#pragma unroll 1
    for (int rr = 0; rr < 4; ++rr) {          // res pair (rr, rr+4)
        const unsigned short* hb = &xh[rr][0][0];
        f32x16 acc0, acc1;
#pragma unroll
        for (int e = 0; e < 16; ++e) { acc0[e] = 0.f; acc1[e] = 0.f; }

        int aoff = aoff_base;
        int c0   = 8 * hA;

        // prime B buffer (kc = 0)
        half8 bfrag;
        {
            union { uint4 u; half8 h; } c;
            c.u = wf[fbase]; bfrag = c.h;
        }

#pragma unroll 1
        for (int kc = 0; kc < 15; ++kc) {
            const int kn = (kc < 14) ? kc + 1 : kc;
            half8 b_n;
            {
                union { uint4 u; half8 h; } c;
                c.u = wf[fbase + 2 * kn]; b_n = c.h;
            }

            // res = rr: 16B-aligned b128; res = rr+4: +4 cols, 2x b64
            half8 ah0 = *reinterpret_cast<const half8*>(hb + aoff);
            half4v h0 = *reinterpret_cast<const half4v*>(hb + aoff + 4);
            half4v h1 = *reinterpret_cast<const half4v*>(hb + aoff + 8);
            half8 ah1 = __builtin_shufflevector(h0, h1, 0, 1, 2, 3, 4, 5, 6, 7);

            acc0 = __builtin_amdgcn_mfma_f32_32x32x16_f16(ah0, bfrag, acc0, 0, 0, 0);
            acc1 = __builtin_amdgcn_mfma_f32_32x32x16_f16(ah1, bfrag, acc1, 0, 0, 0);

            bfrag = b_n;
            aoff += 16; c0 += 16;
            if (c0 >= 40) { c0 -= 40; aoff += XC - 40; }
        }

        // ---- epilogue: repair borderline, set pool bits (both res) ----
#pragma unroll
        for (int half_ = 0; half_ < 2; ++half_) {
            const f32x16 acc = half_ ? acc1 : acc0;
            const int res = rr + 4 * half_;
            const int fm  = ft * 32 + n32;
#pragma unroll
            for (int reg = 0; reg < 16; ++reg) {
                float v = acc[reg];
                const int m   = (reg & 3) + 8 * (reg >> 2) + 4 * hA;
                const int pcg = w0 + res + 8 * m;
                const bool valid = (fm < FM) && (pcg <= 2007);
                if (valid && __builtin_fabsf(v - THRESH) < MARGIN) {
                    float pot = 0.f;
#pragma unroll 1
                    for (int r2 = 0; r2 < 6; ++r2) {
                        const float* xr = x + ((size_t)tt * H_ + rowbase + j_p + r2) * WD_ + pcg;
                        const float* wr = Wg + (size_t)sec * FM * 240 + (size_t)fm * 240 + r2 * 40;
#pragma unroll 1
                        for (int c = 0; c < 40; ++c)
                            pot = fmaf(xr[c], wr[c], pot);
                    }
                    v = pot;
                }
                if (v > THRESH)
                    mask |= 1u << (reg + 16 * half_);  // bit = reg + 16*(res>>2)
            }
        }
    }

    lmask[wid][L] = mask;
    __syncthreads();

    // ---- cross-wave OR (over j_p) + pooled write + fused argmin ----
    int mykey = 0x7fffffff;
    for (int e = tid; e < 4096; e += 512) {
        const int fmo = e >> 6, p = e & 63;       // p = 2m + (res>>2)
        const int rh  = p & 1, m = p >> 1;
        const int hA2 = (m >> 2) & 1;
        const int reg = (m & 3) + 4 * (m >> 3);
        const int lane = 32 * hA2 + (fmo & 31);
        const int ftg  = fmo >> 5;
        const int bit  = reg + 16 * rh;
        const unsigned bits = lmask[4 * ftg + 0][lane] | lmask[4 * ftg + 1][lane] |
                              lmask[4 * ftg + 2][lane] | lmask[4 * ftg + 3][lane];
        const int pg  = coltile * 64 + p;
        const int spk = (bits >> bit) & 1u;
        if (fmo < FM && pg < WP) {
            out[((size_t)(sec * T_ + tt) * FM + fmo) * WP + pg] = spk ? 1.0f : 0.0f;
            if (spk) mykey = min(mykey, fmo * WP + pg);
        }
    }
    int v = mykey;
#pragma unroll
    for (int off = 32; off > 0; off >>= 1)
        v = min(v, __shfl_down(v, off, 64));
    if (L == 0) wmin[wid] = v;
    __syncthreads();
    if (tid == 0) {
        int m = wmin[0];
#pragma unroll
        for (int i = 1; i < 8; ++i) m = min(m, wmin[i]);
        if (m != 0x7fffffff)
            atomicMin(&keys[sec], (tt << 15) | m);
    }
}

// ---------------- Kernel D: finalize winners ----------------
__global__ void finalize_kernel(const int* __restrict__ ws, float* __restrict__ out)
{
    const int i = threadIdx.x;
    if (i < NSEC) {
        const int key = ws[i];
        float feat;
        if (key == 0x7fffffff) feat = -1.0f;
        else                   feat = (float)((key & 32767) / WP);
        out[POOLED_SIZE + i] = feat;
    }
}

extern "C" void kernel_launch(void* const* d_in, const int* in_sizes, int n_in,
                              void* d_out, int out_size, void* d_ws, size_t ws_size,
                              hipStream_t stream) {
    const float* x  = (const float*)d_in[0];
    const float* Wg = (const float*)d_in[1];
    float* out = (float*)d_out;
    int*   wsi = (int*)d_ws;
    uint4* wf  = (uint4*)((char*)d_ws + 256);   // 276 KB needed; ws is ample

    prep_kernel<<<dim3(68), dim3(256), 0, stream>>>(Wg, wsi, wf);
    conv_pool_kernel<<<dim3(2160), dim3(512), 0, stream>>>(x, Wg, wf, out, wsi);
    finalize_kernel<<<dim3(1), dim3(16), 0, stream>>>(wsi, out);
}

// Round 15
// 462.828 us; speedup vs baseline: 1.0973x; 1.0973x over previous
//
#include <hip/hip_runtime.h>

#define T_ 30
#define H_ 41
#define WD_ 2048
#define NSEC 9
#define FM 50
#define WP 502
#define THRESH 23.0f
#define POOLED_SIZE (NSEC * T_ * FM * WP)   // 6,777,000
#define MARGIN 0.0625f                      // ~19 sigma of fp16-input error
#define BFM 52                              // fm slots in B frag store (50 used)
#define NFRAG (NSEC * 30 * BFM)             // 14,040 fragments
#define XC 296                              // LDS cols per shift plane
#define XROWS 9

typedef _Float16 half8 __attribute__((ext_vector_type(8)));
typedef _Float16 half4v __attribute__((ext_vector_type(4)));
typedef float f32x16 __attribute__((ext_vector_type(16)));

__device__ __forceinline__ unsigned short f32_to_f16u(float f) {
    union { _Float16 h; unsigned short u; } cv;
    cv.h = (_Float16)f;
    return cv.u;
}

// ---------------- prep: W -> fp16 frags, layout [sec][oct 0..29][fm 0..51] --
// frag (sec,o,fm) = taps t0=8o..8o+7 of weight row-major (6x40=240).
// Also inits the 9 argmin keys.
__global__ __launch_bounds__(256) void prep_kernel(
    const float* __restrict__ Wg, int* __restrict__ wsi,
    uint4* __restrict__ wf)
{
    const int gid = blockIdx.x * 256 + threadIdx.x;
    if (gid < NSEC) wsi[gid] = 0x7fffffff;
    if (gid >= NFRAG) return;
    const int sec = gid / (30 * BFM);
    const int rem = gid % (30 * BFM);
    const int o   = rem / BFM;
    const int fm  = rem % BFM;
    const bool valid = fm < FM;
    const float* wp = Wg + ((size_t)sec * FM + (valid ? fm : 0)) * 240 + o * 8;
    float4 wa = *reinterpret_cast<const float4*>(wp);
    float4 wb = *reinterpret_cast<const float4*>(wp + 4);
    float f[8] = {wa.x, wa.y, wa.z, wa.w, wb.x, wb.y, wb.z, wb.w};
    unsigned short hu[8];
#pragma unroll
    for (int i = 0; i < 8; ++i)
        hu[i] = f32_to_f16u(valid ? f[i] : 0.f);
    wf[gid] = *reinterpret_cast<uint4*>(hu);
}

// ---------------- Kernel A: fp16 MFMA conv + fire + pool + argmin ---------
// R12-verified tiling (8 waves = j_p x ft; res pairs (rr, rr+4); A layout
// m=lane&31, k=8*(lane>>5)+j; C/D col=lane&31, row=(reg&3)+8*(reg>>2)+
// 4*(lane>>5)); fp16 single-MFMA numerics verified R14 (absmax 0).
// R15: B frags staged in LDS ([oct][fm] -> lane-consecutive 16B reads,
// conflict-free) so the kc loop has NO global ops. R14's regression (465us
// at 1/3 the MFMA work) proved the per-kc global B load's L2 latency was
// the bound all along; LDS B + 3 blocks/CU (48 KB) fixes the K-loop shape.
__global__ __launch_bounds__(512) void conv_pool_kernel(
    const float* __restrict__ x, const float* __restrict__ Wg,
    const uint4* __restrict__ wf,
    float* __restrict__ out, int* __restrict__ keys)
{
    __shared__ __align__(16) unsigned short xh[4][XROWS][XC];  // 20.8 KB
    __shared__ __align__(16) unsigned short Bl[30 * BFM * 8];  // 24.4 KB
    __shared__ unsigned lmask[8][64];
    __shared__ int wmin[8];

    const int b       = blockIdx.x;
    const int coltile = b & 7;             // 8 coltiles * 256 pot cols
    const int tt      = (b >> 3) % T_;
    const int sec     = b / 240;
    const int w0      = coltile * 256;
    const int rowbase = 4 * sec;           // rows used <= 40 < 41
    const int tid     = threadIdx.x;

    // ---- stage B frags for this sec: 1560 uint4 from ws (L2-hot) ----
    {
        const uint4* src = wf + sec * (30 * BFM);
        uint4* dst = reinterpret_cast<uint4*>(Bl);
        for (int i = tid; i < 30 * BFM; i += 512)
            dst[i] = src[i];
    }

    // ---- stage x: 9 rows x 296 cols -> fp16, 4 shifted copies ----
    for (int i = tid; i < XROWS * 74; i += 512) {
        const int row = i / 74;
        const int c4  = i % 74;
        const int gc  = w0 + 4 * c4;
        float4 v;
        if (gc + 3 < WD_) {
            v = *reinterpret_cast<const float4*>(
                x + ((size_t)tt * H_ + rowbase + row) * WD_ + gc);
        } else {
            v.x = v.y = v.z = v.w = 0.f;
        }
        float f[4] = {v.x, v.y, v.z, v.w};
        unsigned short hq[4];
#pragma unroll
        for (int e = 0; e < 4; ++e) hq[e] = f32_to_f16u(f[e]);
#pragma unroll
        for (int S = 0; S < 4; ++S)
#pragma unroll
            for (int e = 0; e < 4; ++e) {
                const int j = 4 * c4 + e - S;
                if (j >= 0 && j < XC) xh[S][row][j] = hq[e];
            }
    }
    __syncthreads();

    const int L   = tid & 63;
    const int wid = tid >> 6;
    const int j_p = wid & 3;        // pot row
    const int ft  = wid >> 2;       // fm tile (32 fm each)
    const int n32 = L & 31;         // A: m; B/C/D: n
    const int hA  = L >> 5;         // k-offset 8*hA; C/D row += 4*hA

    const int fm   = ft * 32 + n32;
    const int fmc  = fm < BFM ? fm : BFM - 1;   // clamp (cols >=50 discarded)
    const int aoff_base = j_p * XC + 8 * hA + 8 * n32;
    // B u16 offset at kc=0: o = hA  ->  (hA*BFM + fmc)*8 ; +2*BFM*8 per kc
    const int boff_base = (hA * BFM + fmc) * 8;

    unsigned mask = 0;

#pragma unroll 1
    for (int rr = 0; rr < 4; ++rr) {          // res pair (rr, rr+4)
        const unsigned short* hb = &xh[rr][0][0];
        f32x16 acc0, acc1;
#pragma unroll
        for (int e = 0; e < 16; ++e) { acc0[e] = 0.f; acc1[e] = 0.f; }

        int aoff = aoff_base;
        int boff = boff_base;
        int c0   = 8 * hA;

#pragma unroll 1
        for (int kc = 0; kc < 15; ++kc) {
            half8 bfrag = *reinterpret_cast<const half8*>(Bl + boff);

            // res = rr: 16B-aligned b128; res = rr+4: +4 cols, 2x b64
            half8 ah0 = *reinterpret_cast<const half8*>(hb + aoff);
            half4v h0 = *reinterpret_cast<const half4v*>(hb + aoff + 4);
            half4v h1 = *reinterpret_cast<const half4v*>(hb + aoff + 8);
            half8 ah1 = __builtin_shufflevector(h0, h1, 0, 1, 2, 3, 4, 5, 6, 7);

            acc0 = __builtin_amdgcn_mfma_f32_32x32x16_f16(ah0, bfrag, acc0, 0, 0, 0);
            acc1 = __builtin_amdgcn_mfma_f32_32x32x16_f16(ah1, bfrag, acc1, 0, 0, 0);

            boff += 2 * BFM * 8;
            aoff += 16; c0 += 16;
            if (c0 >= 40) { c0 -= 40; aoff += XC - 40; }
        }

        // ---- epilogue: repair borderline, set pool bits (both res) ----
#pragma unroll
        for (int half_ = 0; half_ < 2; ++half_) {
            const f32x16 acc = half_ ? acc1 : acc0;
            const int res = rr + 4 * half_;
#pragma unroll
            for (int reg = 0; reg < 16; ++reg) {
                float v = acc[reg];
                const int m   = (reg & 3) + 8 * (reg >> 2) + 4 * hA;
                const int pcg = w0 + res + 8 * m;
                const bool valid = (fm < FM) && (pcg <= 2007);
                if (valid && __builtin_fabsf(v - THRESH) < MARGIN) {
                    float pot = 0.f;
#pragma unroll 1
                    for (int r2 = 0; r2 < 6; ++r2) {
                        const float* xr = x + ((size_t)tt * H_ + rowbase + j_p + r2) * WD_ + pcg;
                        const float* wr = Wg + (size_t)sec * FM * 240 + (size_t)fm * 240 + r2 * 40;
#pragma unroll 1
                        for (int c = 0; c < 40; ++c)
                            pot = fmaf(xr[c], wr[c], pot);
                    }
                    v = pot;
                }
                if (v > THRESH)
                    mask |= 1u << (reg + 16 * half_);  // bit = reg + 16*(res>>2)
            }
        }
    }

    lmask[wid][L] = mask;
    __syncthreads();

    // ---- cross-wave OR (over j_p) + pooled write + fused argmin ----
    int mykey = 0x7fffffff;
    for (int e = tid; e < 4096; e += 512) {
        const int fmo = e >> 6, p = e & 63;       // p = 2m + (res>>2)
        const int rh  = p & 1, m = p >> 1;
        const int hA2 = (m >> 2) & 1;
        const int reg = (m & 3) + 4 * (m >> 3);
        const int lane = 32 * hA2 + (fmo & 31);
        const int ftg  = fmo >> 5;
        const int bit  = reg + 16 * rh;
        const unsigned bits = lmask[4 * ftg + 0][lane] | lmask[4 * ftg + 1][lane] |
                              lmask[4 * ftg + 2][lane] | lmask[4 * ftg + 3][lane];
        const int pg  = coltile * 64 + p;
        const int spk = (bits >> bit) & 1u;
        if (fmo < FM && pg < WP) {
            out[((size_t)(sec * T_ + tt) * FM + fmo) * WP + pg] = spk ? 1.0f : 0.0f;
            if (spk) mykey = min(mykey, fmo * WP + pg);
        }
    }
    int v = mykey;
#pragma unroll
    for (int off = 32; off > 0; off >>= 1)
        v = min(v, __shfl_down(v, off, 64));
    if (L == 0) wmin[wid] = v;
    __syncthreads();
    if (tid == 0) {
        int m = wmin[0];
#pragma unroll
        for (int i = 1; i < 8; ++i) m = min(m, wmin[i]);
        if (m != 0x7fffffff)
            atomicMin(&keys[sec], (tt << 15) | m);
    }
}

// ---------------- Kernel D: finalize winners ----------------
__global__ void finalize_kernel(const int* __restrict__ ws, float* __restrict__ out)
{
    const int i = threadIdx.x;
    if (i < NSEC) {
        const int key = ws[i];
        float feat;
        if (key == 0x7fffffff) feat = -1.0f;
        else                   feat = (float)((key & 32767) / WP);
        out[POOLED_SIZE + i] = feat;
    }
}

extern "C" void kernel_launch(void* const* d_in, const int* in_sizes, int n_in,
                              void* d_out, int out_size, void* d_ws, size_t ws_size,
                              hipStream_t stream) {
    const float* x  = (const float*)d_in[0];
    const float* Wg = (const float*)d_in[1];
    float* out = (float*)d_out;
    int*   wsi = (int*)d_ws;
    uint4* wf  = (uint4*)((char*)d_ws + 256);   // 225 KB needed; ws is ample

    prep_kernel<<<dim3(55), dim3(256), 0, stream>>>(Wg, wsi, wf);
    conv_pool_kernel<<<dim3(2160), dim3(512), 0, stream>>>(x, Wg, wf, out, wsi);
    finalize_kernel<<<dim3(1), dim3(16), 0, stream>>>(wsi, out);
}